// Round 1
// baseline (336.185 us; speedup 1.0000x reference)
//
#include <hip/hip_runtime.h>

#define VXC 0.2f
#define VYC 0.2f
#define XMINC -51.2f
#define YMINC -51.2f
#define GXD 512
#define GYD 512
#define NVOXD (GXD * GYD)
#define BN_EPS 1e-3f

// Pass 1: per-point voxel id -> accumulate (sum_x, sum_y, sum_z, count) per voxel.
__global__ void pillar_pass1(const float* __restrict__ pts, float* __restrict__ acc,
                             int B, int N) {
    int i = blockIdx.x * blockDim.x + threadIdx.x;
    int total = B * N;
    if (i >= total) return;
    int b = i / N;
    float x = pts[(size_t)i * 3 + 0];
    float y = pts[(size_t)i * 3 + 1];
    float z = pts[(size_t)i * 3 + 2];
    // Bit-exact with reference: floor((x - X_MIN)/VX), clip to [0, 511]
    int ix = (int)floorf((x - XMINC) / VXC); ix = min(max(ix, 0), GXD - 1);
    int iy = (int)floorf((y - YMINC) / VYC); iy = min(max(iy, 0), GYD - 1);
    int vid = ix * GYD + iy;
    float* a = acc + (((size_t)b * NVOXD + vid) << 2);
    atomicAdd(a + 0, x);
    atomicAdd(a + 1, y);
    atomicAdd(a + 2, z);
    atomicAdd(a + 3, 1.0f);
}

// Pass 2: one thread per (point, channel). 64 lanes of a wave share one point,
// so the per-point loads are wave-uniform broadcasts. Adds sign * h_c / count
// into out -> accumulates the signed scatter-mean directly (g1 - g0).
__global__ void pillar_pass2(const float* __restrict__ pts, const float* __restrict__ acc,
                             const float* __restrict__ Wm, const float* __restrict__ gamma,
                             const float* __restrict__ beta, const float* __restrict__ mean,
                             const float* __restrict__ var, float* __restrict__ out,
                             float sign, int B, int N) {
    int g = blockIdx.x * blockDim.x + threadIdx.x;  // over B*N*64 (12.8M fits int)
    int total = B * N * 64;
    if (g >= total) return;
    int c = g & 63;
    int i = g >> 6;
    int b = i / N;

    float x = pts[(size_t)i * 3 + 0];  // wave-uniform address -> broadcast
    float y = pts[(size_t)i * 3 + 1];
    float z = pts[(size_t)i * 3 + 2];

    int ix = (int)floorf((x - XMINC) / VXC); ix = min(max(ix, 0), GXD - 1);
    int iy = (int)floorf((y - YMINC) / VYC); iy = min(max(iy, 0), GYD - 1);
    int vid = ix * GYD + iy;

    const float4 s = ((const float4*)acc)[(size_t)b * NVOXD + vid];  // wave-uniform
    float cnt = s.w;              // >= 1 (this point is in the voxel)
    float inv = 1.0f / cnt;
    float cmx = s.x * inv, cmy = s.y * inv, cmz = s.z * inv;

    float cx = ((float)ix + 0.5f) * VXC + XMINC;
    float cy = ((float)iy + 0.5f) * VYC + YMINC;
    // Z_CENTER = 0 -> z - 0 = z

    float f0 = x, f1 = y, f2 = z;
    float f3 = x - cmx, f4 = y - cmy, f5 = z - cmz;
    float f6 = x - cx, f7 = y - cy, f8 = z;

    // h_c = f . W[:, c]; lanes read consecutive c -> coalesced, L1-hot (2.3 KB)
    float h = f0 * Wm[0 * 64 + c];
    h += f1 * Wm[1 * 64 + c];
    h += f2 * Wm[2 * 64 + c];
    h += f3 * Wm[3 * 64 + c];
    h += f4 * Wm[4 * 64 + c];
    h += f5 * Wm[5 * 64 + c];
    h += f6 * Wm[6 * 64 + c];
    h += f7 * Wm[7 * 64 + c];
    h += f8 * Wm[8 * 64 + c];

    h = gamma[c] * (h - mean[c]) * (1.0f / sqrtf(var[c] + BN_EPS)) + beta[c];
    h = fmaxf(h, 0.0f);

    atomicAdd(out + ((((size_t)b * NVOXD + vid) << 6) + c), sign * h * inv);
}

extern "C" void kernel_launch(void* const* d_in, const int* in_sizes, int n_in,
                              void* d_out, int out_size, void* d_ws, size_t ws_size,
                              hipStream_t stream) {
    const float* pc0   = (const float*)d_in[0];
    const float* pc1   = (const float*)d_in[1];
    const float* Wm    = (const float*)d_in[2];
    const float* gamma = (const float*)d_in[3];
    const float* beta  = (const float*)d_in[4];
    const float* mean  = (const float*)d_in[5];
    const float* var   = (const float*)d_in[6];
    float* out = (float*)d_out;

    int B = out_size / (NVOXD * 64);        // = 2
    int N = in_sizes[0] / (3 * B);          // = 100000

    float* acc0 = (float*)d_ws;                       // [B][NVOX][4]
    float* acc1 = acc0 + (size_t)B * NVOXD * 4;       // [B][NVOX][4]
    size_t acc_bytes = (size_t)B * NVOXD * 4 * sizeof(float);

    // ws and out are poisoned 0xAA before every call -> zero them here.
    hipMemsetAsync(d_ws, 0, 2 * acc_bytes, stream);
    hipMemsetAsync(d_out, 0, (size_t)out_size * sizeof(float), stream);

    int total1 = B * N;
    dim3 blk(256);
    dim3 grd1((total1 + 255) / 256);
    pillar_pass1<<<grd1, blk, 0, stream>>>(pc0, acc0, B, N);
    pillar_pass1<<<grd1, blk, 0, stream>>>(pc1, acc1, B, N);

    int total2 = B * N * 64;
    dim3 grd2((total2 + 255) / 256);
    pillar_pass2<<<grd2, blk, 0, stream>>>(pc0, acc0, Wm, gamma, beta, mean, var,
                                           out, -1.0f, B, N);
    pillar_pass2<<<grd2, blk, 0, stream>>>(pc1, acc1, Wm, gamma, beta, mean, var,
                                           out, +1.0f, B, N);
}

// Round 2
// 275.301 us; speedup vs baseline: 1.2212x; 1.2212x over previous
//
#include <hip/hip_runtime.h>

#define VXC 0.2f
#define VYC 0.2f
#define XMINC -51.2f
#define YMINC -51.2f
#define GXD 512
#define GYD 512
#define NVOXD (GXD * GYD)
#define BN_EPS 1e-3f

// Build per-voxel linked lists for both clouds in one launch.
// head[cloud][b][voxel] (init -1 via 0xFF memset), next[cloud][b*N + i].
__global__ void build_lists(const float* __restrict__ pc0, const float* __restrict__ pc1,
                            int* __restrict__ head, int* __restrict__ next,
                            int B, int N) {
    int i = blockIdx.x * blockDim.x + threadIdx.x;
    int per_cloud = B * N;
    int total = 2 * per_cloud;
    if (i >= total) return;
    int cloud = (i >= per_cloud) ? 1 : 0;
    int i2 = i - cloud * per_cloud;           // point index within cloud: [0, B*N)
    int b = i2 / N;
    const float* pts = cloud ? pc1 : pc0;
    float x = pts[(size_t)i2 * 3 + 0];
    float y = pts[(size_t)i2 * 3 + 1];
    // Bit-exact with reference binning: floor((x - X_MIN)/VX), clip [0, 511]
    int ix = (int)floorf((x - XMINC) / VXC); ix = min(max(ix, 0), GXD - 1);
    int iy = (int)floorf((y - YMINC) / VYC); iy = min(max(iy, 0), GYD - 1);
    int vid = ix * GYD + iy;
    int hidx = (cloud * B + b) * NVOXD + vid;
    int old = atomicExch(head + hidx, i2);
    next[cloud * per_cloud + i2] = old;
}

// One wave per (b, voxel); lane = channel. Walk both clouds' point lists:
// pass A sums xyz (cluster mean), pass B computes h per channel and sums.
// Writes out[b][voxel][c] = hsum1/cnt1 - hsum0/cnt0 densely (zeros if empty).
__global__ __launch_bounds__(256)
void gather_finalize(const float* __restrict__ pc0, const float* __restrict__ pc1,
                     const int* __restrict__ head, const int* __restrict__ next,
                     const float* __restrict__ Wm, const float* __restrict__ gamma,
                     const float* __restrict__ beta, const float* __restrict__ mean,
                     const float* __restrict__ var, float* __restrict__ out,
                     int B, int N) {
    int t = blockIdx.x * blockDim.x + threadIdx.x;
    int c = t & 63;
    int w = t >> 6;                  // (b, voxel) id in [0, B*NVOX)
    if (w >= B * NVOXD) return;
    int b = w / NVOXD;
    int v = w - b * NVOXD;
    int ix = v >> 9;                 // vid = ix*512 + iy
    int iy = v & 511;
    float cx = ((float)ix + 0.5f) * VXC + XMINC;
    float cy = ((float)iy + 0.5f) * VYC + YMINC;

    // Per-channel constants (coalesced, L1-hot across blocks)
    float w0 = Wm[0 * 64 + c], w1 = Wm[1 * 64 + c], w2 = Wm[2 * 64 + c];
    float w3 = Wm[3 * 64 + c], w4 = Wm[4 * 64 + c], w5 = Wm[5 * 64 + c];
    float w6 = Wm[6 * 64 + c], w7 = Wm[7 * 64 + c], w8 = Wm[8 * 64 + c];
    float scale = gamma[c] * (1.0f / sqrtf(var[c] + BN_EPS));
    float mu = mean[c], bet = beta[c];

    int per_cloud = B * N;
    float res = 0.0f;

    #pragma unroll
    for (int cloud = 0; cloud < 2; ++cloud) {
        const float* pts = cloud ? pc1 : pc0;
        const int* nx = next + cloud * per_cloud;
        int h0 = head[(cloud * B + b) * NVOXD + v];   // wave-uniform
        if (h0 < 0) continue;

        // Pass A: count + xyz sums (wave-uniform pointer chase)
        int cnt = 0;
        float sx = 0.0f, sy = 0.0f, sz = 0.0f;
        for (int j = h0; j >= 0; j = nx[j]) {
            const float* p = pts + (size_t)j * 3;
            sx += p[0]; sy += p[1]; sz += p[2];
            ++cnt;
        }
        float invc = 1.0f / (float)cnt;
        float cmx = sx * invc, cmy = sy * invc, cmz = sz * invc;

        // Pass B: per-channel h accumulation (xyz reloads are L1 hits)
        float hsum = 0.0f;
        for (int j = h0; j >= 0; j = nx[j]) {
            const float* p = pts + (size_t)j * 3;
            float x = p[0], y = p[1], z = p[2];
            float h = x * w0 + y * w1 + z * w2
                    + (x - cmx) * w3 + (y - cmy) * w4 + (z - cmz) * w5
                    + (x - cx) * w6 + (y - cy) * w7 + z * w8;
            h = (h - mu) * scale + bet;
            hsum += fmaxf(h, 0.0f);
        }
        res += (cloud ? 1.0f : -1.0f) * hsum * invc;
    }

    __builtin_nontemporal_store(res, out + ((size_t)w << 6) + c);
}

extern "C" void kernel_launch(void* const* d_in, const int* in_sizes, int n_in,
                              void* d_out, int out_size, void* d_ws, size_t ws_size,
                              hipStream_t stream) {
    const float* pc0   = (const float*)d_in[0];
    const float* pc1   = (const float*)d_in[1];
    const float* Wm    = (const float*)d_in[2];
    const float* gamma = (const float*)d_in[3];
    const float* beta  = (const float*)d_in[4];
    const float* mean  = (const float*)d_in[5];
    const float* var   = (const float*)d_in[6];
    float* out = (float*)d_out;

    int B = out_size / (NVOXD * 64);        // = 2
    int N = in_sizes[0] / (3 * B);          // = 100000

    int* head = (int*)d_ws;                           // [2][B][NVOX]
    int* next = head + (size_t)2 * B * NVOXD;         // [2][B*N]
    size_t head_bytes = (size_t)2 * B * NVOXD * sizeof(int);

    // head := -1 (ws is poisoned 0xAA each call). next needs no init.
    hipMemsetAsync(head, 0xFF, head_bytes, stream);

    int total_pts = 2 * B * N;
    build_lists<<<(total_pts + 255) / 256, 256, 0, stream>>>(pc0, pc1, head, next, B, N);

    long long total_thr = (long long)B * NVOXD * 64;
    int grd = (int)((total_thr + 255) / 256);
    gather_finalize<<<grd, 256, 0, stream>>>(pc0, pc1, head, next, Wm, gamma, beta,
                                             mean, var, out, B, N);
}